// Round 7
// baseline (20.864 us; speedup 1.0000x reference)
//
#include <hip/hip_runtime.h>

// Bootstrap proposal (time != 0 branch), constants folded for L1=L2=M1=M2=1.
// Per particle [tq1, tq2, th1, th2, v1, v2]:
//   c  = cos(th2)
//   acc1 = (12*tq1 - 6*(3c+2)*tq2) / (16 - 9c^2)
//   acc2 = (12*(5+3c)*tq2 - 6*(3c+2)*tq1) / (16 - 9c^2)
//   mean = prev + DT*[0, 0, v1, v2, acc1, acc2]
//
// AoS [B*P, 6] f32 = groups of 3 float4 per 2 particles. Each OUTPUT float4
// depends on itself + ONE neighbor float4 (see phase table in round 5).
// One (thread, iteration) per output float4: 2 loads, branch-free phase
// selects, 1 contiguous nontemporal store. No LDS, no sync.
//
// Round-6 change: grid-stride, 3 float4 per thread (4096 blocks instead of
// 12288). Each iteration sweeps a contiguous 1M-float4 region; unrolled so
// all 6 loads are in flight before the cos/divide chain (more MLP, less
// dispatch ramp).

#define DT 0.01f

typedef float f4 __attribute__((ext_vector_type(4)));

__device__ __forceinline__ f4 phase_step(const f4* __restrict__ in4, int idx) {
    const int phase = idx % 3;               // 0,1,2 within the 2-particle group
    const f4 a = in4[idx];                   // self
    const f4 b = in4[idx + ((phase == 0) ? 1 : -1)];  // neighbor

    // accel inputs: phase1 -> tq=b.xy, th2=b.w ; phase2 -> tq=b.zw, th2=a.y
    const float th2  = (phase == 1) ? b.w : a.y;
    const float tq1  = (phase == 1) ? b.x : b.z;
    const float tq2  = (phase == 1) ? b.y : b.w;
    const float c    = cosf(th2);
    const float rden = 1.0f / (16.0f - 9.0f * c * c);   // = 1/(36*det)
    const float s    = 6.0f * (3.0f * c + 2.0f);        // = 36*d01
    const float acc1 = (12.0f * tq1 - s * tq2) * rden;
    const float acc2 = (12.0f * (5.0f + 3.0f * c) * tq2 - s * tq1) * rden;

    const float sx = (phase == 0) ? 0.0f : ((phase == 1) ? acc1 : a.z);
    const float sy = (phase == 0) ? 0.0f : ((phase == 1) ? acc2 : a.w);
    const float sz = (phase == 0) ? b.x  : ((phase == 1) ? 0.0f : acc1);
    const float sw = (phase == 0) ? b.y  : ((phase == 1) ? 0.0f : acc2);

    f4 o;
    o.x = a.x + DT * sx;
    o.y = a.y + DT * sy;
    o.z = a.z + DT * sz;
    o.w = a.w + DT * sw;
    return o;
}

__global__ void __launch_bounds__(256)
bootstrap_proposal_kernel(const f4* __restrict__ in4,
                          f4* __restrict__ out4,
                          int nvec, int stride) {
    const int tid = blockIdx.x * 256 + threadIdx.x;
#pragma unroll
    for (int it = 0; it < 3; ++it) {
        const int idx = tid + it * stride;
        if (idx < nvec) {
            const f4 o = phase_step(in4, idx);
            __builtin_nontemporal_store(o, &out4[idx]);
        }
    }
}

extern "C" void kernel_launch(void* const* d_in, const int* in_sizes, int n_in,
                              void* d_out, int out_size, void* d_ws, size_t ws_size,
                              hipStream_t stream) {
    const float* in = (const float*)d_in[0];   // [B*P, 6] f32
    float* out = (float*)d_out;                // [B*P, 6] f32
    const int nvec = out_size / 4;             // total float4 (divisible by 3)
    // 3 float4 per thread; stride = total threads so each iter is contiguous.
    const int nthreads = (nvec + 2) / 3;
    const int grid = (nthreads + 255) / 256;
    const int stride = grid * 256;
    bootstrap_proposal_kernel<<<grid, 256, 0, stream>>>(
        (const f4*)in, (f4*)out, nvec, stride);
}